// Round 3
// baseline (228.559 us; speedup 1.0000x reference)
//
#include <hip/hip_runtime.h>
#include <hip/hip_bf16.h>
#include <math.h>

typedef __bf16 bf16;
typedef __bf16 bf16x4 __attribute__((ext_vector_type(4)));
typedef __bf16 bf16x8 __attribute__((ext_vector_type(8)));
typedef float  f32x4  __attribute__((ext_vector_type(4)));
typedef unsigned u32x2 __attribute__((ext_vector_type(2)));
typedef unsigned u32x4 __attribute__((ext_vector_type(4)));

#define T_SEQ 2048
#define E_DIM 1024
#define H_NUM 16
#define D_DIM 64
#define NDELTA 4095
#define PB_STRIDE 4100
#define LOG2E 1.4426950408889634f

__device__ __forceinline__ void gld16(const bf16* g, bf16* l) {
  __builtin_amdgcn_global_load_lds((__attribute__((address_space(1))) void*)(g),
                                   (__attribute__((address_space(3))) void*)(l), 16, 0, 0);
}

// in-register qd-group exchange via official gfx950 builtins
__device__ __forceinline__ void qswap(unsigned &a, unsigned &b) {
  u32x2 t  = __builtin_amdgcn_permlane32_swap(a, b, false, false);
  u32x2 t2 = __builtin_amdgcn_permlane16_swap(t[0], t[1], false, false);
  a = t2[0]; b = t2[1];
}

// ---------------- fp32 -> bf16 cast (hidden_states) ----------------
__global__ void cast_bf16_kernel(const float* __restrict__ src, bf16* __restrict__ dst, int n4) {
  int i = blockIdx.x * blockDim.x + threadIdx.x;
  if (i >= n4) return;
  const float4 v = reinterpret_cast<const float4*>(src)[i];
  bf16x4 o;
  o[0] = (bf16)v.x; o[1] = (bf16)v.y; o[2] = (bf16)v.z; o[3] = (bf16)v.w;
  reinterpret_cast<bf16x4*>(dst)[i] = o;
}

// ---------------- all 4 weight casts in one launch; q/k/v into concat buffer ----------------
__global__ void cast_w_kernel(const float* __restrict__ q_w, const float* __restrict__ k_w,
                              const float* __restrict__ v_w, const float* __restrict__ o_w,
                              bf16* __restrict__ wcat, bf16* __restrict__ wob) {
  int i = blockIdx.x * 256 + threadIdx.x;   // 0..262143 float4 groups
  int sel = blockIdx.y;
  const float* src = (sel == 0) ? q_w : (sel == 1) ? k_w : (sel == 2) ? v_w : o_w;
  bf16* dst = (sel < 3) ? (wcat + (size_t)sel * 1048576) : wob;
  const float4 v = reinterpret_cast<const float4*>(src)[i];
  bf16x4 o;
  o[0] = (bf16)v.x; o[1] = (bf16)v.y; o[2] = (bf16)v.z; o[3] = (bf16)v.w;
  reinterpret_cast<bf16x4*>(dst)[i] = o;
}

// ---------------- position-bias table, 4 phase-shifted copies ----------------
// copy p, head h lives at pbt + (p*16+h)*PB_STRIDE + ((p+1)&3); word j = pb(delta = j-2047).
// Phase offset makes lane (lm&3 == p) reads of g(r=0) (== 3-p mod 4) 16B-aligned.
__global__ void pb_kernel(const float* __restrict__ rel_embed, float* __restrict__ pbt) {
  int dd = blockIdx.x * 64 + threadIdx.x;
  if (dd >= NDELTA) return;
  int delta = dd - (T_SEQ - 1);
  int bucket = (delta > 0) ? 160 : 0;
  int rel = abs(delta);
  int v;
  if (rel < 80) {
    v = rel;
  } else {
    float rf = (float)(rel < 1 ? 1 : rel);
    float lf = logf(rf / 80.0f) * (80.0f / 2.302585092994046f);
    int lg = 80 + (int)lf;
    v = lg < 159 ? lg : 159;
  }
  bucket += v;
#pragma unroll
  for (int h = 0; h < H_NUM; h++) {
    float val = rel_embed[bucket * H_NUM + h];
#pragma unroll
    for (int p = 0; p < 4; p++)
      pbt[(size_t)(p * 16 + h) * PB_STRIDE + ((p + 1) & 3) + dd] = val;
  }
}

// ---------------- gate (output pre-multiplied by LOG2E) ----------------
__global__ __launch_bounds__(256)
void gate_kernel(const float* __restrict__ hs, const float* __restrict__ gru_w,
                 const float* __restrict__ gru_b, const float* __restrict__ gconst,
                 float* __restrict__ gate)
{
  __shared__ float w[512];
  int tid = threadIdx.x;
  w[tid] = gru_w[tid];
  w[tid + 256] = gru_w[tid + 256];
  __syncthreads();
  int idx = blockIdx.x * 256 + tid;
  int h  = idx & 15;
  int bt = idx >> 4;
  const float* x = hs + (size_t)bt * E_DIM + h * D_DIM;
  float acc[8] = {0,0,0,0,0,0,0,0};
  for (int d = 0; d < 64; d += 4) {
    float4 xv = *(const float4*)&x[d];
#pragma unroll
    for (int e = 0; e < 8; e++) {
      acc[e] += xv.x * w[e*64+d] + xv.y * w[e*64+d+1]
              + xv.z * w[e*64+d+2] + xv.w * w[e*64+d+3];
    }
  }
  float p0 = acc[0]+acc[1]+acc[2]+acc[3] + gru_b[0]+gru_b[1]+gru_b[2]+gru_b[3];
  float p1 = acc[4]+acc[5]+acc[6]+acc[7] + gru_b[4]+gru_b[5]+gru_b[6]+gru_b[7];
  float ga = 1.0f / (1.0f + expf(-p0));
  float gb = 1.0f / (1.0f + expf(-p1));
  float g = (ga * (gb * gconst[h] - 1.0f) + 2.0f) * LOG2E;
  int bb = bt >> 11;
  int t  = bt & (T_SEQ - 1);
  gate[((size_t)(bb * H_NUM + h)) * T_SEQ + t] = g;
}

// ---------------- GEMM v2: global_load_lds staging (m97-style), 128x128x32 ----------------
template<int MODE, int N_TOTAL>
__global__ __launch_bounds__(256)
void gemm2_kernel(const bf16* __restrict__ A, const bf16* __restrict__ W,
                  const float* __restrict__ b0, const float* __restrict__ b1,
                  const float* __restrict__ b2, float qalpha,
                  void* __restrict__ out0, void* __restrict__ out1, void* __restrict__ out2)
{
  __shared__ bf16 As[128 * 32];   // unpadded: required by global_load_lds lane mapping
  __shared__ bf16 Bs[128 * 32];
  const int tid  = threadIdx.x;
  const int lane = tid & 63;
  const int wave = tid >> 6;
  const int m0 = blockIdx.y * 128;
  const int n0 = blockIdx.x * 128;
  const int wm = (wave >> 1) * 64;
  const int wn = (wave & 1) * 64;
  const int qd = lane >> 4;
  const int lm = lane & 15;

  const int row4 = lane >> 2;
  const int col8 = (lane & 3) * 8;
  const bf16* gA0 = A + (size_t)(m0 + wave * 32 + row4) * 1024 + col8;
  const bf16* gA1 = gA0 + (size_t)16 * 1024;
  const bf16* gB0 = W + (size_t)(n0 + wave * 32 + row4) * 1024 + col8;
  const bf16* gB1 = gB0 + (size_t)16 * 1024;
  bf16* lA0 = As + (wave * 2 + 0) * 512;
  bf16* lA1 = As + (wave * 2 + 1) * 512;
  bf16* lB0 = Bs + (wave * 2 + 0) * 512;
  bf16* lB1 = Bs + (wave * 2 + 1) * 512;

  f32x4 acc[4][4] = {};

  for (int k0 = 0; k0 < 1024; k0 += 32) {
    gld16(gA0 + k0, lA0);
    gld16(gA1 + k0, lA1);
    gld16(gB0 + k0, lB0);
    gld16(gB1 + k0, lB1);
    __syncthreads();
    bf16x8 af[4], bfr[4];
#pragma unroll
    for (int i = 0; i < 4; i++) {
      af[i]  = *(const bf16x8*)&As[(wm + i * 16 + lm) * 32 + qd * 8];
      bfr[i] = *(const bf16x8*)&Bs[(wn + i * 16 + lm) * 32 + qd * 8];
    }
#pragma unroll
    for (int im = 0; im < 4; im++)
#pragma unroll
      for (int in = 0; in < 4; in++)
        acc[im][in] = __builtin_amdgcn_mfma_f32_16x16x32_bf16(af[im], bfr[in], acc[im][in], 0, 0, 0);
    __syncthreads();
  }

  const int seg = n0 >> 10;
  const float* bias = (MODE == 0) ? b0 : (seg == 0 ? b0 : (seg == 1 ? b1 : b2));
  const float alpha = (MODE == 1 && seg == 0) ? qalpha : 1.0f;

#pragma unroll
  for (int im = 0; im < 4; im++) {
#pragma unroll
    for (int in = 0; in < 4; in++) {
      const int n  = n0 + wn + in * 16 + lm;
      const int n1 = n & 1023;
      const float bv = bias[n1];
      const int mb = m0 + wm + im * 16 + qd * 4;
      if (MODE == 0) {
        float* o = (float*)out0;
#pragma unroll
        for (int r = 0; r < 4; r++)
          o[(size_t)(mb + r) * 1024 + n1] = acc[im][in][r] + bv;
      } else if (seg == 2) {
        const int bb = mb >> 11;
        const int t  = mb & 2047;
        bf16x4 pk;
#pragma unroll
        for (int r = 0; r < 4; r++) pk[r] = (bf16)(acc[im][in][r] + bv);
        *(bf16x4*)&((bf16*)out2)[((size_t)(bb * 1024 + n1)) * 2048 + t] = pk;
      } else {
        bf16* o = (bf16*)(seg == 0 ? out0 : out1);
#pragma unroll
        for (int r = 0; r < 4; r++)
          o[(size_t)(mb + r) * 1024 + n1] = (bf16)((acc[im][in][r] + bv) * alpha);
      }
    }
  }
}

// ---------------- flash attention v5: pb served from L2 via vmem, not LDS ----------------
// In-register P redistribution (round 2) + position bias loaded as aligned
// global_load_dwordx4 from the 4-phase-copy table. g = s-q+2047 is always in
// [0,4094] so no bounds check. Removes 32 ds_read_b32/wave-iter + pbs staging.
#define LK 72
__global__ __launch_bounds__(256)
void attn3_kernel(const bf16* __restrict__ Qg, const bf16* __restrict__ Kg,
                  const bf16* __restrict__ Vtg, const float* __restrict__ gate,
                  const float* __restrict__ pbt, bf16* __restrict__ ctx)
{
  __shared__ bf16 Ks[2][64 * LK];
  __shared__ bf16 Vs[2][64 * LK];

  const int t0 = blockIdx.x * 128;
  const int h  = blockIdx.y;
  const int b  = blockIdx.z;
  const int tid  = threadIdx.x;
  const int lane = tid & 63;
  const int wave = tid >> 6;
  const int qd = lane >> 4;
  const int lm = lane & 15;

  // per-lane pb base pointer: addr(word) = PL + s0 - nb*16 + 16*mb, always >= 0
  // and 16B-aligned (phase offset (p+1)&3 cancels g(r=0) mod 4 == 3-p).
  const int pp = lm & 3;
  const float* pb_base = pbt + (size_t)(pp * 16 + h) * PB_STRIDE + ((pp + 1) & 3)
                         + 4 * qd + 2047 - t0 - wave * 32 - lm;

  bf16x8 qf[2][2];
  float g[2];
#pragma unroll
  for (int nb = 0; nb < 2; nb++) {
    const int q = t0 + wave * 32 + nb * 16 + lm;
    const bf16* qrow = Qg + (size_t)(b * T_SEQ + q) * E_DIM + h * D_DIM;
    qf[nb][0] = *(const bf16x8*)(qrow + qd * 8);
    qf[nb][1] = *(const bf16x8*)(qrow + 32 + qd * 8);
    g[nb] = gate[((size_t)(b * H_NUM + h)) * T_SEQ + q];
  }

  const int srow = tid >> 2;
  const int scol = (tid & 3) * 16;
  const bf16* kgp = Kg  + ((size_t)(b * T_SEQ) + srow) * E_DIM + h * D_DIM + scol;
  const bf16* vgp = Vtg + ((size_t)(b * 1024) + h * D_DIM + srow) * T_SEQ + scol;

  {
    bf16x8 a0 = *(const bf16x8*)kgp;
    bf16x8 a1 = *(const bf16x8*)(kgp + 8);
    bf16x8 c0 = *(const bf16x8*)vgp;
    bf16x8 c1 = *(const bf16x8*)(vgp + 8);
    *(bf16x8*)&Ks[0][srow * LK + scol]     = a0;
    *(bf16x8*)&Ks[0][srow * LK + scol + 8] = a1;
    *(bf16x8*)&Vs[0][srow * LK + scol]     = c0;
    *(bf16x8*)&Vs[0][srow * LK + scol + 8] = c1;
  }
  __syncthreads();

  f32x4 o[4][2] = {};
  float li[2] = {0.0f, 0.0f};

  for (int it = 0; it < T_SEQ / 64; it++) {
    const int s0 = it * 64;
    const int buf = it & 1;
    const bool more = (it + 1 < T_SEQ / 64);
    bf16x8 nk0, nk1, nv0, nv1;
    if (more) {
      const bf16* kn = kgp + (size_t)(s0 + 64) * E_DIM;
      const bf16* vn = vgp + (s0 + 64);
      nk0 = *(const bf16x8*)kn; nk1 = *(const bf16x8*)(kn + 8);
      nv0 = *(const bf16x8*)vn; nv1 = *(const bf16x8*)(vn + 8);
    }

    bf16x8 kf[4][2];
#pragma unroll
    for (int mb = 0; mb < 4; mb++) {
      kf[mb][0] = *(const bf16x8*)&Ks[buf][(16 * mb + lm) * LK + qd * 8];
      kf[mb][1] = *(const bf16x8*)&Ks[buf][(16 * mb + lm) * LK + 32 + qd * 8];
    }

    bf16x8 pf[2][2];
#pragma unroll
    for (int nb = 0; nb < 2; nb++) {
      // position-bias: 4 aligned dwordx4 from L2 (vmem pipe, independent of MFMA)
      f32x4 pbv[4];
#pragma unroll
      for (int mb = 0; mb < 4; mb++)
        pbv[mb] = *(const f32x4*)(pb_base + s0 - nb * 16 + 16 * mb);

      f32x4 sc[4];
#pragma unroll
      for (int mb = 0; mb < 4; mb++) {
        f32x4 t = {};
        t = __builtin_amdgcn_mfma_f32_16x16x32_bf16(kf[mb][0], qf[nb][0], t, 0, 0, 0);
        t = __builtin_amdgcn_mfma_f32_16x16x32_bf16(kf[mb][1], qf[nb][1], t, 0, 0, 0);
        sc[mb] = t;
      }
      float rs = 0.0f;
      unsigned wlo[4], whi[4];
#pragma unroll
      for (int mb = 0; mb < 4; mb++) {
        bf16x4 pk;
#pragma unroll
        for (int r = 0; r < 4; r++) {
          float p = __builtin_amdgcn_exp2f(sc[mb][r] + g[nb] * pbv[mb][r]);
          rs += p;
          pk[r] = (bf16)p;
        }
        u32x2 pw = __builtin_bit_cast(u32x2, pk);
        wlo[mb] = pw[0]; whi[mb] = pw[1];
      }
      li[nb] += rs;
      // half 0: k = 0..31 from (mb0, mb1)
      unsigned a0 = wlo[0], b0v = wlo[1], a1 = whi[0], b1v = whi[1];
      qswap(a0, b0v);
      qswap(a1, b1v);
      u32x4 h0; h0[0] = a0; h0[1] = a1; h0[2] = b0v; h0[3] = b1v;
      pf[nb][0] = __builtin_bit_cast(bf16x8, h0);
      // half 1: k = 32..63 from (mb2, mb3)
      unsigned c0 = wlo[2], d0v = wlo[3], c1 = whi[2], d1v = whi[3];
      qswap(c0, d0v);
      qswap(c1, d1v);
      u32x4 h1; h1[0] = c0; h1[1] = c1; h1[2] = d0v; h1[3] = d1v;
      pf[nb][1] = __builtin_bit_cast(bf16x8, h1);
    }

#pragma unroll
    for (int db = 0; db < 4; db++) {
      bf16x8 vf0 = *(const bf16x8*)&Vs[buf][(16 * db + lm) * LK + qd * 8];
      bf16x8 vf1 = *(const bf16x8*)&Vs[buf][(16 * db + lm) * LK + 32 + qd * 8];
#pragma unroll
      for (int nb = 0; nb < 2; nb++) {
        o[db][nb] = __builtin_amdgcn_mfma_f32_16x16x32_bf16(vf0, pf[nb][0], o[db][nb], 0, 0, 0);
        o[db][nb] = __builtin_amdgcn_mfma_f32_16x16x32_bf16(vf1, pf[nb][1], o[db][nb], 0, 0, 0);
      }
    }
    if (more) {
      *(bf16x8*)&Ks[buf ^ 1][srow * LK + scol]     = nk0;
      *(bf16x8*)&Ks[buf ^ 1][srow * LK + scol + 8] = nk1;
      *(bf16x8*)&Vs[buf ^ 1][srow * LK + scol]     = nv0;
      *(bf16x8*)&Vs[buf ^ 1][srow * LK + scol + 8] = nv1;
    }
    __syncthreads();
  }

#pragma unroll
  for (int nb = 0; nb < 2; nb++) {
    li[nb] += __shfl_xor(li[nb], 16);
    li[nb] += __shfl_xor(li[nb], 32);
  }
#pragma unroll
  for (int nb = 0; nb < 2; nb++) {
    const float inv = 1.0f / li[nb];
    const int q = t0 + wave * 32 + nb * 16 + lm;
    bf16* obase = ctx + (size_t)(b * T_SEQ + q) * E_DIM + h * D_DIM + 4 * qd;
#pragma unroll
    for (int db = 0; db < 4; db++) {
      bf16x4 ov;
      ov[0] = (bf16)(o[db][nb][0] * inv); ov[1] = (bf16)(o[db][nb][1] * inv);
      ov[2] = (bf16)(o[db][nb][2] * inv); ov[3] = (bf16)(o[db][nb][3] * inv);
      *(bf16x4*)&obase[16 * db] = ov;
    }
  }
}

// ---------------- orchestration ----------------
extern "C" void kernel_launch(void* const* d_in, const int* in_sizes, int n_in,
                              void* d_out, int out_size, void* d_ws, size_t ws_size,
                              hipStream_t stream)
{
  const float* hs     = (const float*)d_in[0];
  const float* q_w    = (const float*)d_in[1];
  const float* q_b    = (const float*)d_in[2];
  const float* k_w    = (const float*)d_in[3];
  const float* k_b    = (const float*)d_in[4];
  const float* v_w    = (const float*)d_in[5];
  const float* v_b    = (const float*)d_in[6];
  const float* out_w  = (const float*)d_in[7];
  const float* out_b  = (const float*)d_in[8];
  const float* rel    = (const float*)d_in[9];
  const float* gconst = (const float*)d_in[10];
  const float* gru_w  = (const float*)d_in[11];
  const float* gru_b  = (const float*)d_in[12];

  char* p = (char*)d_ws;
  bf16* hsb  = (bf16*)p; p += (size_t)4096 * 1024 * 2;
  bf16* wcat = (bf16*)p; p += (size_t)3072 * 1024 * 2;
  bf16* wob  = (bf16*)p; p += (size_t)1024 * 1024 * 2;
  bf16* Qb   = (bf16*)p; p += (size_t)4096 * 1024 * 2;
  bf16* Kb   = (bf16*)p; p += (size_t)4096 * 1024 * 2;
  bf16* Vtb  = (bf16*)p; p += (size_t)2048 * 2048 * 2;
  bf16* ctxb = (bf16*)p; p += (size_t)4096 * 1024 * 2;
  float* gatep = (float*)p; p += (size_t)2 * H_NUM * T_SEQ * 4;
  float* pbt   = (float*)p; p += (size_t)4 * H_NUM * PB_STRIDE * 4;

  cast_bf16_kernel<<<4096, 256, 0, stream>>>(hs, hsb, 1048576);
  cast_w_kernel<<<dim3(1024, 4), 256, 0, stream>>>(q_w, k_w, v_w, out_w, wcat, wob);
  pb_kernel<<<64, 64, 0, stream>>>(rel, pbt);
  gate_kernel<<<256, 256, 0, stream>>>(hs, gru_w, gru_b, gconst, gatep);

  const float qalpha = 0.125f * LOG2E;
  gemm2_kernel<1, 3072><<<dim3(24, 32), 256, 0, stream>>>(
      hsb, wcat, q_b, k_b, v_b, qalpha, Qb, Kb, Vtb);

  attn3_kernel<<<dim3(T_SEQ / 128, H_NUM, 2), 256, 0, stream>>>(Qb, Kb, Vtb, gatep, pbt, ctxb);

  gemm2_kernel<0, 1024><<<dim3(8, 32), 256, 0, stream>>>(
      ctxb, wob, out_b, nullptr, nullptr, 1.0f, d_out, nullptr, nullptr);
}

// Round 4
// 228.419 us; speedup vs baseline: 1.0006x; 1.0006x over previous
//
#include <hip/hip_runtime.h>
#include <hip/hip_bf16.h>
#include <math.h>

typedef __bf16 bf16;
typedef __bf16 bf16x4 __attribute__((ext_vector_type(4)));
typedef __bf16 bf16x8 __attribute__((ext_vector_type(8)));
typedef float  f32x4  __attribute__((ext_vector_type(4)));
typedef unsigned u32x2 __attribute__((ext_vector_type(2)));
typedef unsigned u32x4 __attribute__((ext_vector_type(4)));

#define T_SEQ 2048
#define E_DIM 1024
#define H_NUM 16
#define D_DIM 64
#define NDELTA 4095
#define LOG2E 1.4426950408889634f

__device__ __forceinline__ void gld16(const bf16* g, bf16* l) {
  __builtin_amdgcn_global_load_lds((__attribute__((address_space(1))) void*)(g),
                                   (__attribute__((address_space(3))) void*)(l), 16, 0, 0);
}

// in-register qd-group exchange via official gfx950 builtins
__device__ __forceinline__ void qswap(unsigned &a, unsigned &b) {
  u32x2 t  = __builtin_amdgcn_permlane32_swap(a, b, false, false);
  u32x2 t2 = __builtin_amdgcn_permlane16_swap(t[0], t[1], false, false);
  a = t2[0]; b = t2[1];
}

// ---------------- fp32 -> bf16 cast (hidden_states) ----------------
__global__ void cast_bf16_kernel(const float* __restrict__ src, bf16* __restrict__ dst, int n4) {
  int i = blockIdx.x * blockDim.x + threadIdx.x;
  if (i >= n4) return;
  const float4 v = reinterpret_cast<const float4*>(src)[i];
  bf16x4 o;
  o[0] = (bf16)v.x; o[1] = (bf16)v.y; o[2] = (bf16)v.z; o[3] = (bf16)v.w;
  reinterpret_cast<bf16x4*>(dst)[i] = o;
}

// ---------------- all 4 weight casts in one launch; q/k/v into concat buffer ----------------
__global__ void cast_w_kernel(const float* __restrict__ q_w, const float* __restrict__ k_w,
                              const float* __restrict__ v_w, const float* __restrict__ o_w,
                              bf16* __restrict__ wcat, bf16* __restrict__ wob) {
  int i = blockIdx.x * 256 + threadIdx.x;   // 0..262143 float4 groups
  int sel = blockIdx.y;
  const float* src = (sel == 0) ? q_w : (sel == 1) ? k_w : (sel == 2) ? v_w : o_w;
  bf16* dst = (sel < 3) ? (wcat + (size_t)sel * 1048576) : wob;
  const float4 v = reinterpret_cast<const float4*>(src)[i];
  bf16x4 o;
  o[0] = (bf16)v.x; o[1] = (bf16)v.y; o[2] = (bf16)v.z; o[3] = (bf16)v.w;
  reinterpret_cast<bf16x4*>(dst)[i] = o;
}

// ---------------- position-bias table pbt[h][delta+2047] ----------------
__global__ void pb_kernel(const float* __restrict__ rel_embed, float* __restrict__ pbt) {
  int dd = blockIdx.x * 64 + threadIdx.x;
  if (dd >= NDELTA) return;
  int delta = dd - (T_SEQ - 1);
  int bucket = (delta > 0) ? 160 : 0;
  int rel = abs(delta);
  int v;
  if (rel < 80) {
    v = rel;
  } else {
    float rf = (float)(rel < 1 ? 1 : rel);
    float lf = logf(rf / 80.0f) * (80.0f / 2.302585092994046f);
    int lg = 80 + (int)lf;
    v = lg < 159 ? lg : 159;
  }
  bucket += v;
#pragma unroll
  for (int h = 0; h < H_NUM; h++)
    pbt[h * NDELTA + dd] = rel_embed[bucket * H_NUM + h];
}

// ---------------- gate (output pre-multiplied by LOG2E) ----------------
__global__ __launch_bounds__(256)
void gate_kernel(const float* __restrict__ hs, const float* __restrict__ gru_w,
                 const float* __restrict__ gru_b, const float* __restrict__ gconst,
                 float* __restrict__ gate)
{
  __shared__ float w[512];
  int tid = threadIdx.x;
  w[tid] = gru_w[tid];
  w[tid + 256] = gru_w[tid + 256];
  __syncthreads();
  int idx = blockIdx.x * 256 + tid;
  int h  = idx & 15;
  int bt = idx >> 4;
  const float* x = hs + (size_t)bt * E_DIM + h * D_DIM;
  float acc[8] = {0,0,0,0,0,0,0,0};
  for (int d = 0; d < 64; d += 4) {
    float4 xv = *(const float4*)&x[d];
#pragma unroll
    for (int e = 0; e < 8; e++) {
      acc[e] += xv.x * w[e*64+d] + xv.y * w[e*64+d+1]
              + xv.z * w[e*64+d+2] + xv.w * w[e*64+d+3];
    }
  }
  float p0 = acc[0]+acc[1]+acc[2]+acc[3] + gru_b[0]+gru_b[1]+gru_b[2]+gru_b[3];
  float p1 = acc[4]+acc[5]+acc[6]+acc[7] + gru_b[4]+gru_b[5]+gru_b[6]+gru_b[7];
  float ga = 1.0f / (1.0f + expf(-p0));
  float gb = 1.0f / (1.0f + expf(-p1));
  float g = (ga * (gb * gconst[h] - 1.0f) + 2.0f) * LOG2E;
  int bb = bt >> 11;
  int t  = bt & (T_SEQ - 1);
  gate[((size_t)(bb * H_NUM + h)) * T_SEQ + t] = g;
}

// ---------------- GEMM v2: global_load_lds staging (m97-style), 128x128x32 ----------------
template<int MODE, int N_TOTAL>
__global__ __launch_bounds__(256)
void gemm2_kernel(const bf16* __restrict__ A, const bf16* __restrict__ W,
                  const float* __restrict__ b0, const float* __restrict__ b1,
                  const float* __restrict__ b2, float qalpha,
                  void* __restrict__ out0, void* __restrict__ out1, void* __restrict__ out2)
{
  __shared__ bf16 As[128 * 32];   // unpadded: required by global_load_lds lane mapping
  __shared__ bf16 Bs[128 * 32];
  const int tid  = threadIdx.x;
  const int lane = tid & 63;
  const int wave = tid >> 6;
  const int m0 = blockIdx.y * 128;
  const int n0 = blockIdx.x * 128;
  const int wm = (wave >> 1) * 64;
  const int wn = (wave & 1) * 64;
  const int qd = lane >> 4;
  const int lm = lane & 15;

  const int row4 = lane >> 2;
  const int col8 = (lane & 3) * 8;
  const bf16* gA0 = A + (size_t)(m0 + wave * 32 + row4) * 1024 + col8;
  const bf16* gA1 = gA0 + (size_t)16 * 1024;
  const bf16* gB0 = W + (size_t)(n0 + wave * 32 + row4) * 1024 + col8;
  const bf16* gB1 = gB0 + (size_t)16 * 1024;
  bf16* lA0 = As + (wave * 2 + 0) * 512;
  bf16* lA1 = As + (wave * 2 + 1) * 512;
  bf16* lB0 = Bs + (wave * 2 + 0) * 512;
  bf16* lB1 = Bs + (wave * 2 + 1) * 512;

  f32x4 acc[4][4] = {};

  for (int k0 = 0; k0 < 1024; k0 += 32) {
    gld16(gA0 + k0, lA0);
    gld16(gA1 + k0, lA1);
    gld16(gB0 + k0, lB0);
    gld16(gB1 + k0, lB1);
    __syncthreads();
    bf16x8 af[4], bfr[4];
#pragma unroll
    for (int i = 0; i < 4; i++) {
      af[i]  = *(const bf16x8*)&As[(wm + i * 16 + lm) * 32 + qd * 8];
      bfr[i] = *(const bf16x8*)&Bs[(wn + i * 16 + lm) * 32 + qd * 8];
    }
#pragma unroll
    for (int im = 0; im < 4; im++)
#pragma unroll
      for (int in = 0; in < 4; in++)
        acc[im][in] = __builtin_amdgcn_mfma_f32_16x16x32_bf16(af[im], bfr[in], acc[im][in], 0, 0, 0);
    __syncthreads();
  }

  const int seg = n0 >> 10;
  const float* bias = (MODE == 0) ? b0 : (seg == 0 ? b0 : (seg == 1 ? b1 : b2));
  const float alpha = (MODE == 1 && seg == 0) ? qalpha : 1.0f;

#pragma unroll
  for (int im = 0; im < 4; im++) {
#pragma unroll
    for (int in = 0; in < 4; in++) {
      const int n  = n0 + wn + in * 16 + lm;
      const int n1 = n & 1023;
      const float bv = bias[n1];
      const int mb = m0 + wm + im * 16 + qd * 4;
      if (MODE == 0) {
        float* o = (float*)out0;
#pragma unroll
        for (int r = 0; r < 4; r++)
          o[(size_t)(mb + r) * 1024 + n1] = acc[im][in][r] + bv;
      } else if (seg == 2) {
        const int bb = mb >> 11;
        const int t  = mb & 2047;
        bf16x4 pk;
#pragma unroll
        for (int r = 0; r < 4; r++) pk[r] = (bf16)(acc[im][in][r] + bv);
        *(bf16x4*)&((bf16*)out2)[((size_t)(bb * 1024 + n1)) * 2048 + t] = pk;
      } else {
        bf16* o = (bf16*)(seg == 0 ? out0 : out1);
#pragma unroll
        for (int r = 0; r < 4; r++)
          o[(size_t)(mb + r) * 1024 + n1] = (bf16)((acc[im][in][r] + bv) * alpha);
      }
    }
  }
}

// ---------------- flash attention v6 ----------------
// Round-2 structure (LDS pbs, in-register P redistribution) with K/V staging
// switched to global_load_lds (no VGPR round-trip, no ds_write):
//   LDS tile is linear [64 rows][8 chunks of 16B]; lane l of a wave stages
//   row (w*16+j*8+(l>>3)), and reads GLOBAL chunk ((l&7)^(l>>3)) so that
//   LDS[row][c] = G[row][c ^ (row&7)]  (both-sides XOR swizzle, rule 21).
//   Fragment reads address chunk ((qd+4*half) ^ (row&7)) -> 8 lanes per
//   chunk-group at distinct rows = 8 accesses/bank = b128 floor (conflict-free).
// T5: s_setprio(1) around the QK and PV MFMA clusters.
__global__ __launch_bounds__(256)
void attn3_kernel(const bf16* __restrict__ Qg, const bf16* __restrict__ Kg,
                  const bf16* __restrict__ Vtg, const float* __restrict__ gate,
                  const float* __restrict__ pbt, bf16* __restrict__ ctx)
{
  __shared__ bf16 Ks[2][64 * 64];
  __shared__ bf16 Vs[2][64 * 64];
  __shared__ float pbs[2176];

  const int t0 = blockIdx.x * 128;
  const int h  = blockIdx.y;
  const int b  = blockIdx.z;
  const int tid  = threadIdx.x;
  const int lane = tid & 63;
  const int wave = tid >> 6;
  const int qd = lane >> 4;
  const int lm = lane & 15;

  for (int i = tid; i < 2176; i += 256) {
    int idx = i - t0 + 1920;
    pbs[i] = (idx >= 0 && idx < NDELTA) ? pbt[h * NDELTA + idx] : 0.0f;
  }

  bf16x8 qf[2][2];
  float g[2];
#pragma unroll
  for (int nb = 0; nb < 2; nb++) {
    const int q = t0 + wave * 32 + nb * 16 + lm;
    const bf16* qrow = Qg + (size_t)(b * T_SEQ + q) * E_DIM + h * D_DIM;
    qf[nb][0] = *(const bf16x8*)(qrow + qd * 8);
    qf[nb][1] = *(const bf16x8*)(qrow + 32 + qd * 8);
    g[nb] = gate[((size_t)(b * H_NUM + h)) * T_SEQ + q];
  }

  // staging geometry: wave w covers rows [w*16, w*16+16) of the 64-row tile,
  // two gld16 per operand (8 rows each). Per-lane swizzled global chunk.
  const int sr = lane >> 3;                 // row within 8-row group
  const int sc = ((lane & 7) ^ sr) * 8;     // swizzled source chunk (bf16 elems)
  // K rows: s-index, stride E_DIM; V rows: d-index, stride T_SEQ
  const bf16* kg0 = Kg  + ((size_t)(b * T_SEQ) + wave * 16 + sr) * E_DIM + h * D_DIM + sc;
  const bf16* kg1 = kg0 + (size_t)8 * E_DIM;
  const bf16* vg0 = Vtg + ((size_t)(b * 1024) + h * D_DIM + wave * 16 + sr) * T_SEQ + sc;
  const bf16* vg1 = vg0 + (size_t)8 * T_SEQ;
  const int l0 = (wave * 16 + 0) * 64;
  const int l1 = (wave * 16 + 8) * 64;

  // prologue: stage tile 0 into buf 0
  gld16(kg0, &Ks[0][l0]);
  gld16(kg1, &Ks[0][l1]);
  gld16(vg0, &Vs[0][l0]);
  gld16(vg1, &Vs[0][l1]);
  __syncthreads();

  f32x4 o[4][2] = {};
  float li[2] = {0.0f, 0.0f};
  const int xs = lm & 7;   // read-side XOR (row&7 == lm&7 for rows 16*mb+lm)

  for (int it = 0; it < T_SEQ / 64; it++) {
    const int s0 = it * 64;
    const int buf = it & 1;
    const bool more = (it + 1 < T_SEQ / 64);
    if (more) {
      const size_t ko = (size_t)(s0 + 64) * E_DIM;
      gld16(kg0 + ko, &Ks[buf ^ 1][l0]);
      gld16(kg1 + ko, &Ks[buf ^ 1][l1]);
      gld16(vg0 + (s0 + 64), &Vs[buf ^ 1][l0]);
      gld16(vg1 + (s0 + 64), &Vs[buf ^ 1][l1]);
    }

    bf16x8 kf[4][2];
#pragma unroll
    for (int mb = 0; mb < 4; mb++) {
      kf[mb][0] = *(const bf16x8*)&Ks[buf][(16 * mb + lm) * 64 + ((qd ^ xs) * 8)];
      kf[mb][1] = *(const bf16x8*)&Ks[buf][(16 * mb + lm) * 64 + (((qd + 4) ^ xs) * 8)];
    }

    bf16x8 pf[2][2];
#pragma unroll
    for (int nb = 0; nb < 2; nb++) {
      f32x4 sc4[4];
      __builtin_amdgcn_s_setprio(1);
#pragma unroll
      for (int mb = 0; mb < 4; mb++) {
        f32x4 t = {};
        t = __builtin_amdgcn_mfma_f32_16x16x32_bf16(kf[mb][0], qf[nb][0], t, 0, 0, 0);
        t = __builtin_amdgcn_mfma_f32_16x16x32_bf16(kf[mb][1], qf[nb][1], t, 0, 0, 0);
        sc4[mb] = t;
      }
      __builtin_amdgcn_s_setprio(0);
      const int ib = s0 + 4 * qd + 127 - (wave * 32 + nb * 16 + lm);
      float rs = 0.0f;
      unsigned wlo[4], whi[4];
#pragma unroll
      for (int mb = 0; mb < 4; mb++) {
        bf16x4 pk;
#pragma unroll
        for (int r = 0; r < 4; r++) {
          float p = __builtin_amdgcn_exp2f(sc4[mb][r] + g[nb] * pbs[ib + 16 * mb + r]);
          rs += p;
          pk[r] = (bf16)p;
        }
        u32x2 pw = __builtin_bit_cast(u32x2, pk);
        wlo[mb] = pw[0]; whi[mb] = pw[1];
      }
      li[nb] += rs;
      // half 0: k = 0..31 from (mb0, mb1)
      unsigned a0 = wlo[0], b0v = wlo[1], a1 = whi[0], b1v = whi[1];
      qswap(a0, b0v);
      qswap(a1, b1v);
      u32x4 h0; h0[0] = a0; h0[1] = a1; h0[2] = b0v; h0[3] = b1v;
      pf[nb][0] = __builtin_bit_cast(bf16x8, h0);
      // half 1: k = 32..63 from (mb2, mb3)
      unsigned c0 = wlo[2], d0v = wlo[3], c1 = whi[2], d1v = whi[3];
      qswap(c0, d0v);
      qswap(c1, d1v);
      u32x4 h1; h1[0] = c0; h1[1] = c1; h1[2] = d0v; h1[3] = d1v;
      pf[nb][1] = __builtin_bit_cast(bf16x8, h1);
    }

    __builtin_amdgcn_s_setprio(1);
#pragma unroll
    for (int db = 0; db < 4; db++) {
      bf16x8 vf0 = *(const bf16x8*)&Vs[buf][(16 * db + lm) * 64 + ((qd ^ xs) * 8)];
      bf16x8 vf1 = *(const bf16x8*)&Vs[buf][(16 * db + lm) * 64 + (((qd + 4) ^ xs) * 8)];
#pragma unroll
      for (int nb = 0; nb < 2; nb++) {
        o[db][nb] = __builtin_amdgcn_mfma_f32_16x16x32_bf16(vf0, pf[nb][0], o[db][nb], 0, 0, 0);
        o[db][nb] = __builtin_amdgcn_mfma_f32_16x16x32_bf16(vf1, pf[nb][1], o[db][nb], 0, 0, 0);
      }
    }
    __builtin_amdgcn_s_setprio(0);
    __syncthreads();   // drains vmcnt (next-tile gld_lds) + LDS reads of buf
  }

#pragma unroll
  for (int nb = 0; nb < 2; nb++) {
    li[nb] += __shfl_xor(li[nb], 16);
    li[nb] += __shfl_xor(li[nb], 32);
  }
#pragma unroll
  for (int nb = 0; nb < 2; nb++) {
    const float inv = 1.0f / li[nb];
    const int q = t0 + wave * 32 + nb * 16 + lm;
    bf16* obase = ctx + (size_t)(b * T_SEQ + q) * E_DIM + h * D_DIM + 4 * qd;
#pragma unroll
    for (int db = 0; db < 4; db++) {
      bf16x4 ov;
      ov[0] = (bf16)(o[db][nb][0] * inv); ov[1] = (bf16)(o[db][nb][1] * inv);
      ov[2] = (bf16)(o[db][nb][2] * inv); ov[3] = (bf16)(o[db][nb][3] * inv);
      *(bf16x4*)&obase[16 * db] = ov;
    }
  }
}

// ---------------- orchestration ----------------
extern "C" void kernel_launch(void* const* d_in, const int* in_sizes, int n_in,
                              void* d_out, int out_size, void* d_ws, size_t ws_size,
                              hipStream_t stream)
{
  const float* hs     = (const float*)d_in[0];
  const float* q_w    = (const float*)d_in[1];
  const float* q_b    = (const float*)d_in[2];
  const float* k_w    = (const float*)d_in[3];
  const float* k_b    = (const float*)d_in[4];
  const float* v_w    = (const float*)d_in[5];
  const float* v_b    = (const float*)d_in[6];
  const float* out_w  = (const float*)d_in[7];
  const float* out_b  = (const float*)d_in[8];
  const float* rel    = (const float*)d_in[9];
  const float* gconst = (const float*)d_in[10];
  const float* gru_w  = (const float*)d_in[11];
  const float* gru_b  = (const float*)d_in[12];

  char* p = (char*)d_ws;
  bf16* hsb  = (bf16*)p; p += (size_t)4096 * 1024 * 2;
  bf16* wcat = (bf16*)p; p += (size_t)3072 * 1024 * 2;
  bf16* wob  = (bf16*)p; p += (size_t)1024 * 1024 * 2;
  bf16* Qb   = (bf16*)p; p += (size_t)4096 * 1024 * 2;
  bf16* Kb   = (bf16*)p; p += (size_t)4096 * 1024 * 2;
  bf16* Vtb  = (bf16*)p; p += (size_t)2048 * 2048 * 2;
  bf16* ctxb = (bf16*)p; p += (size_t)4096 * 1024 * 2;
  float* gatep = (float*)p; p += (size_t)2 * H_NUM * T_SEQ * 4;
  float* pbt   = (float*)p; p += (size_t)H_NUM * NDELTA * 4;

  cast_bf16_kernel<<<4096, 256, 0, stream>>>(hs, hsb, 1048576);
  cast_w_kernel<<<dim3(1024, 4), 256, 0, stream>>>(q_w, k_w, v_w, out_w, wcat, wob);
  pb_kernel<<<64, 64, 0, stream>>>(rel, pbt);
  gate_kernel<<<256, 256, 0, stream>>>(hs, gru_w, gru_b, gconst, gatep);

  const float qalpha = 0.125f * LOG2E;
  gemm2_kernel<1, 3072><<<dim3(24, 32), 256, 0, stream>>>(
      hsb, wcat, q_b, k_b, v_b, qalpha, Qb, Kb, Vtb);

  attn3_kernel<<<dim3(T_SEQ / 128, H_NUM, 2), 256, 0, stream>>>(Qb, Kb, Vtb, gatep, pbt, ctxb);

  gemm2_kernel<0, 1024><<<dim3(8, 32), 256, 0, stream>>>(
      ctxb, wob, out_b, nullptr, nullptr, 1.0f, d_out, nullptr, nullptr);
}

// Round 6
// 219.141 us; speedup vs baseline: 1.0430x; 1.0423x over previous
//
#include <hip/hip_runtime.h>
#include <hip/hip_bf16.h>
#include <math.h>

typedef __bf16 bf16;
typedef __bf16 bf16x4 __attribute__((ext_vector_type(4)));
typedef __bf16 bf16x8 __attribute__((ext_vector_type(8)));
typedef float  f32x4  __attribute__((ext_vector_type(4)));
typedef unsigned u32x2 __attribute__((ext_vector_type(2)));
typedef unsigned u32x4 __attribute__((ext_vector_type(4)));

#define T_SEQ 2048
#define E_DIM 1024
#define H_NUM 16
#define D_DIM 64
#define NDELTA 4095
#define LOG2E 1.4426950408889634f

__device__ __forceinline__ void gld16(const bf16* g, bf16* l) {
  __builtin_amdgcn_global_load_lds((__attribute__((address_space(1))) void*)(g),
                                   (__attribute__((address_space(3))) void*)(l), 16, 0, 0);
}

// in-register qd-group exchange via official gfx950 builtins
__device__ __forceinline__ void qswap(unsigned &a, unsigned &b) {
  u32x2 t  = __builtin_amdgcn_permlane32_swap(a, b, false, false);
  u32x2 t2 = __builtin_amdgcn_permlane16_swap(t[0], t[1], false, false);
  a = t2[0]; b = t2[1];
}

// ---------------- fused fp32->bf16 cast + gate (one block per bt row) ----------------
// Saves the separate 16MB hs re-read of the old gate kernel + one launch.
__global__ __launch_bounds__(256)
void cast_gate_kernel(const float* __restrict__ hs, bf16* __restrict__ hsb,
                      const float* __restrict__ gru_w, const float* __restrict__ gru_b,
                      const float* __restrict__ gconst, float* __restrict__ gate)
{
  __shared__ float w[512];
  const int tid = threadIdx.x;
  const int bt  = blockIdx.x;
  w[tid]       = gru_w[tid];
  w[tid + 256] = gru_w[tid + 256];
  __syncthreads();

  const int i = bt * 256 + tid;
  const float4 xv = reinterpret_cast<const float4*>(hs)[i];
  bf16x4 o;
  o[0] = (bf16)xv.x; o[1] = (bf16)xv.y; o[2] = (bf16)xv.z; o[3] = (bf16)xv.w;
  reinterpret_cast<bf16x4*>(hsb)[i] = o;

  // gate: head h = tid>>4 covers d = (tid&15)*4 .. +3
  const int h  = tid >> 4;
  const int d0 = (tid & 15) * 4;
  float acc[8];
#pragma unroll
  for (int e = 0; e < 8; e++) {
    acc[e] = xv.x * w[e*64+d0] + xv.y * w[e*64+d0+1]
           + xv.z * w[e*64+d0+2] + xv.w * w[e*64+d0+3];
  }
#pragma unroll
  for (int e = 0; e < 8; e++) {
    float v = acc[e];
    v += __shfl_xor(v, 1);
    v += __shfl_xor(v, 2);
    v += __shfl_xor(v, 4);
    v += __shfl_xor(v, 8);
    acc[e] = v;
  }
  if ((tid & 15) == 0) {
    float p0 = acc[0]+acc[1]+acc[2]+acc[3] + gru_b[0]+gru_b[1]+gru_b[2]+gru_b[3];
    float p1 = acc[4]+acc[5]+acc[6]+acc[7] + gru_b[4]+gru_b[5]+gru_b[6]+gru_b[7];
    float ga = 1.0f / (1.0f + expf(-p0));
    float gb = 1.0f / (1.0f + expf(-p1));
    float g = (ga * (gb * gconst[h] - 1.0f) + 2.0f) * LOG2E;
    int bb = bt >> 11;
    int t  = bt & (T_SEQ - 1);
    gate[((size_t)(bb * H_NUM + h)) * T_SEQ + t] = g;
  }
}

// ---------------- weight casts (y=0..3) + position-bias table (y=4) ----------------
__global__ void cast_w_kernel(const float* __restrict__ q_w, const float* __restrict__ k_w,
                              const float* __restrict__ v_w, const float* __restrict__ o_w,
                              bf16* __restrict__ wcat, bf16* __restrict__ wob,
                              const float* __restrict__ rel_embed, float* __restrict__ pbt) {
  int sel = blockIdx.y;
  int tid = threadIdx.x;
  if (sel == 4) {
    int dd = blockIdx.x * 256 + tid;
    if (blockIdx.x >= 16 || dd >= NDELTA) return;
    int delta = dd - (T_SEQ - 1);
    int bucket = (delta > 0) ? 160 : 0;
    int rel = abs(delta);
    int v;
    if (rel < 80) {
      v = rel;
    } else {
      float rf = (float)(rel < 1 ? 1 : rel);
      float lf = logf(rf / 80.0f) * (80.0f / 2.302585092994046f);
      int lg = 80 + (int)lf;
      v = lg < 159 ? lg : 159;
    }
    bucket += v;
#pragma unroll
    for (int h = 0; h < H_NUM; h++)
      pbt[h * NDELTA + dd] = rel_embed[bucket * H_NUM + h];
    return;
  }
  int i = blockIdx.x * 256 + tid;   // 0..262143 float4 groups
  const float* src = (sel == 0) ? q_w : (sel == 1) ? k_w : (sel == 2) ? v_w : o_w;
  bf16* dst = (sel < 3) ? (wcat + (size_t)sel * 1048576) : wob;
  const float4 v = reinterpret_cast<const float4*>(src)[i];
  bf16x4 o;
  o[0] = (bf16)v.x; o[1] = (bf16)v.y; o[2] = (bf16)v.z; o[3] = (bf16)v.w;
  reinterpret_cast<bf16x4*>(dst)[i] = o;
}

// ---------------- GEMM v2: global_load_lds staging (m97-style), 128x128x32 ----------------
// MODE 1 only now: fused QKV (N_TOTAL=3072).
template<int MODE, int N_TOTAL>
__global__ __launch_bounds__(256)
void gemm2_kernel(const bf16* __restrict__ A, const bf16* __restrict__ W,
                  const float* __restrict__ b0, const float* __restrict__ b1,
                  const float* __restrict__ b2, float qalpha,
                  void* __restrict__ out0, void* __restrict__ out1, void* __restrict__ out2)
{
  __shared__ bf16 As[128 * 32];   // unpadded: required by global_load_lds lane mapping
  __shared__ bf16 Bs[128 * 32];
  const int tid  = threadIdx.x;
  const int lane = tid & 63;
  const int wave = tid >> 6;
  const int m0 = blockIdx.y * 128;
  const int n0 = blockIdx.x * 128;
  const int wm = (wave >> 1) * 64;
  const int wn = (wave & 1) * 64;
  const int qd = lane >> 4;
  const int lm = lane & 15;

  const int row4 = lane >> 2;
  const int col8 = (lane & 3) * 8;
  const bf16* gA0 = A + (size_t)(m0 + wave * 32 + row4) * 1024 + col8;
  const bf16* gA1 = gA0 + (size_t)16 * 1024;
  const bf16* gB0 = W + (size_t)(n0 + wave * 32 + row4) * 1024 + col8;
  const bf16* gB1 = gB0 + (size_t)16 * 1024;
  bf16* lA0 = As + (wave * 2 + 0) * 512;
  bf16* lA1 = As + (wave * 2 + 1) * 512;
  bf16* lB0 = Bs + (wave * 2 + 0) * 512;
  bf16* lB1 = Bs + (wave * 2 + 1) * 512;

  f32x4 acc[4][4] = {};

  for (int k0 = 0; k0 < 1024; k0 += 32) {
    gld16(gA0 + k0, lA0);
    gld16(gA1 + k0, lA1);
    gld16(gB0 + k0, lB0);
    gld16(gB1 + k0, lB1);
    __syncthreads();
    bf16x8 af[4], bfr[4];
#pragma unroll
    for (int i = 0; i < 4; i++) {
      af[i]  = *(const bf16x8*)&As[(wm + i * 16 + lm) * 32 + qd * 8];
      bfr[i] = *(const bf16x8*)&Bs[(wn + i * 16 + lm) * 32 + qd * 8];
    }
#pragma unroll
    for (int im = 0; im < 4; im++)
#pragma unroll
      for (int in = 0; in < 4; in++)
        acc[im][in] = __builtin_amdgcn_mfma_f32_16x16x32_bf16(af[im], bfr[in], acc[im][in], 0, 0, 0);
    __syncthreads();
  }

  const int seg = n0 >> 10;
  const float* bias = (MODE == 0) ? b0 : (seg == 0 ? b0 : (seg == 1 ? b1 : b2));
  const float alpha = (MODE == 1 && seg == 0) ? qalpha : 1.0f;

#pragma unroll
  for (int im = 0; im < 4; im++) {
#pragma unroll
    for (int in = 0; in < 4; in++) {
      const int n  = n0 + wn + in * 16 + lm;
      const int n1 = n & 1023;
      const float bv = bias[n1];
      const int mb = m0 + wm + im * 16 + qd * 4;
      if (MODE == 0) {
        float* o = (float*)out0;
#pragma unroll
        for (int r = 0; r < 4; r++)
          o[(size_t)(mb + r) * 1024 + n1] = acc[im][in][r] + bv;
      } else if (seg == 2) {
        const int bb = mb >> 11;
        const int t  = mb & 2047;
        bf16x4 pk;
#pragma unroll
        for (int r = 0; r < 4; r++) pk[r] = (bf16)(acc[im][in][r] + bv);
        *(bf16x4*)&((bf16*)out2)[((size_t)(bb * 1024 + n1)) * 2048 + t] = pk;
      } else {
        bf16* o = (bf16*)(seg == 0 ? out0 : out1);
#pragma unroll
        for (int r = 0; r < 4; r++)
          o[(size_t)(mb + r) * 1024 + n1] = (bf16)((acc[im][in][r] + bv) * alpha);
      }
    }
  }
}

// ---------------- O-projection GEMM: 64x128 tile -> grid (8,64)=512 blocks (2/CU) ----------------
__global__ __launch_bounds__(256)
void gemm_o_kernel(const bf16* __restrict__ A, const bf16* __restrict__ W,
                   const float* __restrict__ bias, float* __restrict__ out)
{
  __shared__ bf16 As[64 * 32];
  __shared__ bf16 Bs[128 * 32];
  const int tid  = threadIdx.x;
  const int lane = tid & 63;
  const int wave = tid >> 6;
  const int m0 = blockIdx.y * 64;
  const int n0 = blockIdx.x * 128;
  const int wm = (wave >> 1) * 32;
  const int wn = (wave & 1) * 64;
  const int qd = lane >> 4;
  const int lm = lane & 15;

  const int row4 = lane >> 2;
  const int col8 = (lane & 3) * 8;
  // A: wave w stages rows [w*16, w*16+16)  (1 gld16)
  const bf16* gA0 = A + (size_t)(m0 + wave * 16 + row4) * 1024 + col8;
  // B: wave w stages rows [w*32, w*32+32)  (2 gld16)
  const bf16* gB0 = W + (size_t)(n0 + wave * 32 + row4) * 1024 + col8;
  const bf16* gB1 = gB0 + (size_t)16 * 1024;
  bf16* lA0 = As + wave * 16 * 32;
  bf16* lB0 = Bs + (wave * 2 + 0) * 512;
  bf16* lB1 = Bs + (wave * 2 + 1) * 512;

  f32x4 acc[2][4] = {};

  for (int k0 = 0; k0 < 1024; k0 += 32) {
    gld16(gA0 + k0, lA0);
    gld16(gB0 + k0, lB0);
    gld16(gB1 + k0, lB1);
    __syncthreads();
    bf16x8 af[2], bfr[4];
#pragma unroll
    for (int i = 0; i < 2; i++)
      af[i]  = *(const bf16x8*)&As[(wm + i * 16 + lm) * 32 + qd * 8];
#pragma unroll
    for (int i = 0; i < 4; i++)
      bfr[i] = *(const bf16x8*)&Bs[(wn + i * 16 + lm) * 32 + qd * 8];
#pragma unroll
    for (int im = 0; im < 2; im++)
#pragma unroll
      for (int in = 0; in < 4; in++)
        acc[im][in] = __builtin_amdgcn_mfma_f32_16x16x32_bf16(af[im], bfr[in], acc[im][in], 0, 0, 0);
    __syncthreads();
  }

#pragma unroll
  for (int im = 0; im < 2; im++) {
#pragma unroll
    for (int in = 0; in < 4; in++) {
      const int n  = n0 + wn + in * 16 + lm;
      const float bv = bias[n];
      const int mb = m0 + wm + im * 16 + qd * 4;
#pragma unroll
      for (int r = 0; r < 4; r++)
        out[(size_t)(mb + r) * 1024 + n] = acc[im][in][r] + bv;
    }
  }
}

// ---------------- flash attention (round-2 exact: LDS pbs + in-register P redistribution) ----------------
#define LK 72
__global__ __launch_bounds__(256)
void attn3_kernel(const bf16* __restrict__ Qg, const bf16* __restrict__ Kg,
                  const bf16* __restrict__ Vtg, const float* __restrict__ gate,
                  const float* __restrict__ pbt, bf16* __restrict__ ctx)
{
  __shared__ bf16 Ks[2][64 * LK];
  __shared__ bf16 Vs[2][64 * LK];
  __shared__ float pbs[2176];

  const int t0 = blockIdx.x * 128;
  const int h  = blockIdx.y;
  const int b  = blockIdx.z;
  const int tid  = threadIdx.x;
  const int lane = tid & 63;
  const int wave = tid >> 6;
  const int qd = lane >> 4;
  const int lm = lane & 15;

  for (int i = tid; i < 2176; i += 256) {
    int idx = i - t0 + 1920;
    pbs[i] = (idx >= 0 && idx < NDELTA) ? pbt[h * NDELTA + idx] : 0.0f;
  }

  bf16x8 qf[2][2];
  float g[2];
#pragma unroll
  for (int nb = 0; nb < 2; nb++) {
    const int q = t0 + wave * 32 + nb * 16 + lm;
    const bf16* qrow = Qg + (size_t)(b * T_SEQ + q) * E_DIM + h * D_DIM;
    qf[nb][0] = *(const bf16x8*)(qrow + qd * 8);
    qf[nb][1] = *(const bf16x8*)(qrow + 32 + qd * 8);
    g[nb] = gate[((size_t)(b * H_NUM + h)) * T_SEQ + q];
  }

  const int srow = tid >> 2;
  const int scol = (tid & 3) * 16;
  const bf16* kgp = Kg  + ((size_t)(b * T_SEQ) + srow) * E_DIM + h * D_DIM + scol;
  const bf16* vgp = Vtg + ((size_t)(b * 1024) + h * D_DIM + srow) * T_SEQ + scol;

  {
    bf16x8 a0 = *(const bf16x8*)kgp;
    bf16x8 a1 = *(const bf16x8*)(kgp + 8);
    bf16x8 c0 = *(const bf16x8*)vgp;
    bf16x8 c1 = *(const bf16x8*)(vgp + 8);
    *(bf16x8*)&Ks[0][srow * LK + scol]     = a0;
    *(bf16x8*)&Ks[0][srow * LK + scol + 8] = a1;
    *(bf16x8*)&Vs[0][srow * LK + scol]     = c0;
    *(bf16x8*)&Vs[0][srow * LK + scol + 8] = c1;
  }
  __syncthreads();

  f32x4 o[4][2] = {};
  float li[2] = {0.0f, 0.0f};

  for (int it = 0; it < T_SEQ / 64; it++) {
    const int s0 = it * 64;
    const int buf = it & 1;
    const bool more = (it + 1 < T_SEQ / 64);
    bf16x8 nk0, nk1, nv0, nv1;
    if (more) {
      const bf16* kn = kgp + (size_t)(s0 + 64) * E_DIM;
      const bf16* vn = vgp + (s0 + 64);
      nk0 = *(const bf16x8*)kn; nk1 = *(const bf16x8*)(kn + 8);
      nv0 = *(const bf16x8*)vn; nv1 = *(const bf16x8*)(vn + 8);
    }

    bf16x8 kf[4][2];
#pragma unroll
    for (int mb = 0; mb < 4; mb++) {
      kf[mb][0] = *(const bf16x8*)&Ks[buf][(16 * mb + lm) * LK + qd * 8];
      kf[mb][1] = *(const bf16x8*)&Ks[buf][(16 * mb + lm) * LK + 32 + qd * 8];
    }

    bf16x8 pf[2][2];
#pragma unroll
    for (int nb = 0; nb < 2; nb++) {
      f32x4 sc[4];
#pragma unroll
      for (int mb = 0; mb < 4; mb++) {
        f32x4 t = {};
        t = __builtin_amdgcn_mfma_f32_16x16x32_bf16(kf[mb][0], qf[nb][0], t, 0, 0, 0);
        t = __builtin_amdgcn_mfma_f32_16x16x32_bf16(kf[mb][1], qf[nb][1], t, 0, 0, 0);
        sc[mb] = t;
      }
      const int ib = s0 + 4 * qd + 127 - (wave * 32 + nb * 16 + lm);
      float rs = 0.0f;
      unsigned wlo[4], whi[4];
#pragma unroll
      for (int mb = 0; mb < 4; mb++) {
        bf16x4 pk;
#pragma unroll
        for (int r = 0; r < 4; r++) {
          float p = __builtin_amdgcn_exp2f(sc[mb][r] + g[nb] * pbs[ib + 16 * mb + r]);
          rs += p;
          pk[r] = (bf16)p;
        }
        u32x2 pw = __builtin_bit_cast(u32x2, pk);
        wlo[mb] = pw[0]; whi[mb] = pw[1];
      }
      li[nb] += rs;
      // half 0: k = 0..31 from (mb0, mb1)
      unsigned a0 = wlo[0], b0v = wlo[1], a1 = whi[0], b1v = whi[1];
      qswap(a0, b0v);
      qswap(a1, b1v);
      u32x4 h0; h0[0] = a0; h0[1] = a1; h0[2] = b0v; h0[3] = b1v;
      pf[nb][0] = __builtin_bit_cast(bf16x8, h0);
      // half 1: k = 32..63 from (mb2, mb3)
      unsigned c0 = wlo[2], d0v = wlo[3], c1 = whi[2], d1v = whi[3];
      qswap(c0, d0v);
      qswap(c1, d1v);
      u32x4 h1; h1[0] = c0; h1[1] = c1; h1[2] = d0v; h1[3] = d1v;
      pf[nb][1] = __builtin_bit_cast(bf16x8, h1);
    }

#pragma unroll
    for (int db = 0; db < 4; db++) {
      bf16x8 vf0 = *(const bf16x8*)&Vs[buf][(16 * db + lm) * LK + qd * 8];
      bf16x8 vf1 = *(const bf16x8*)&Vs[buf][(16 * db + lm) * LK + 32 + qd * 8];
#pragma unroll
      for (int nb = 0; nb < 2; nb++) {
        o[db][nb] = __builtin_amdgcn_mfma_f32_16x16x32_bf16(vf0, pf[nb][0], o[db][nb], 0, 0, 0);
        o[db][nb] = __builtin_amdgcn_mfma_f32_16x16x32_bf16(vf1, pf[nb][1], o[db][nb], 0, 0, 0);
      }
    }
    if (more) {
      *(bf16x8*)&Ks[buf ^ 1][srow * LK + scol]     = nk0;
      *(bf16x8*)&Ks[buf ^ 1][srow * LK + scol + 8] = nk1;
      *(bf16x8*)&Vs[buf ^ 1][srow * LK + scol]     = nv0;
      *(bf16x8*)&Vs[buf ^ 1][srow * LK + scol + 8] = nv1;
    }
    __syncthreads();
  }

#pragma unroll
  for (int nb = 0; nb < 2; nb++) {
    li[nb] += __shfl_xor(li[nb], 16);
    li[nb] += __shfl_xor(li[nb], 32);
  }
#pragma unroll
  for (int nb = 0; nb < 2; nb++) {
    const float inv = 1.0f / li[nb];
    const int q = t0 + wave * 32 + nb * 16 + lm;
    bf16* obase = ctx + (size_t)(b * T_SEQ + q) * E_DIM + h * D_DIM + 4 * qd;
#pragma unroll
    for (int db = 0; db < 4; db++) {
      bf16x4 ov;
      ov[0] = (bf16)(o[db][nb][0] * inv); ov[1] = (bf16)(o[db][nb][1] * inv);
      ov[2] = (bf16)(o[db][nb][2] * inv); ov[3] = (bf16)(o[db][nb][3] * inv);
      *(bf16x4*)&obase[16 * db] = ov;
    }
  }
}

// ---------------- orchestration ----------------
extern "C" void kernel_launch(void* const* d_in, const int* in_sizes, int n_in,
                              void* d_out, int out_size, void* d_ws, size_t ws_size,
                              hipStream_t stream)
{
  const float* hs     = (const float*)d_in[0];
  const float* q_w    = (const float*)d_in[1];
  const float* q_b    = (const float*)d_in[2];
  const float* k_w    = (const float*)d_in[3];
  const float* k_b    = (const float*)d_in[4];
  const float* v_w    = (const float*)d_in[5];
  const float* v_b    = (const float*)d_in[6];
  const float* out_w  = (const float*)d_in[7];
  const float* out_b  = (const float*)d_in[8];
  const float* rel    = (const float*)d_in[9];
  const float* gconst = (const float*)d_in[10];
  const float* gru_w  = (const float*)d_in[11];
  const float* gru_b  = (const float*)d_in[12];

  char* p = (char*)d_ws;
  bf16* hsb  = (bf16*)p; p += (size_t)4096 * 1024 * 2;
  bf16* wcat = (bf16*)p; p += (size_t)3072 * 1024 * 2;
  bf16* wob  = (bf16*)p; p += (size_t)1024 * 1024 * 2;
  bf16* Qb   = (bf16*)p; p += (size_t)4096 * 1024 * 2;
  bf16* Kb   = (bf16*)p; p += (size_t)4096 * 1024 * 2;
  bf16* Vtb  = (bf16*)p; p += (size_t)2048 * 2048 * 2;
  bf16* ctxb = (bf16*)p; p += (size_t)4096 * 1024 * 2;
  float* gatep = (float*)p; p += (size_t)2 * H_NUM * T_SEQ * 4;
  float* pbt   = (float*)p; p += (size_t)H_NUM * NDELTA * 4;

  cast_gate_kernel<<<4096, 256, 0, stream>>>(hs, hsb, gru_w, gru_b, gconst, gatep);
  cast_w_kernel<<<dim3(1024, 5), 256, 0, stream>>>(q_w, k_w, v_w, out_w, wcat, wob, rel, pbt);

  const float qalpha = 0.125f * LOG2E;
  gemm2_kernel<1, 3072><<<dim3(24, 32), 256, 0, stream>>>(
      hsb, wcat, q_b, k_b, v_b, qalpha, Qb, Kb, Vtb);

  attn3_kernel<<<dim3(T_SEQ / 128, H_NUM, 2), 256, 0, stream>>>(Qb, Kb, Vtb, gatep, pbt, ctxb);

  gemm_o_kernel<<<dim3(8, 64), 256, 0, stream>>>(ctxb, wob, out_b, (float*)d_out);
}